// Round 7
// baseline (32.731 us; speedup 1.0000x reference)
//
#include <hip/hip_runtime.h>

// 3D median filter 3x3x3, stride 1, reflect padding.
// x: (2, 1, 160, 160, 160) fp32 -> same shape. Median = rank 13 (0-based) of 27.
// Round 6: async global->LDS staging (global_load_lds, 16B) with a 6-plane LDS
// ring; fills issued one full iteration before consumption so HBM/L2 latency
// hides under the sort/merge network. Compute is the round-5 hf4 packed-f16
// median network (4 x-outputs/thread, merge99 shared by 2 z-outputs).

typedef __fp16 hf2 __attribute__((ext_vector_type(2)));
typedef __fp16 hf4 __attribute__((ext_vector_type(4)));

#define DEV __device__ __forceinline__

DEV hf4 hmin4(hf4 a, hf4 b) { return __builtin_elementwise_min(a, b); }
DEV hf4 hmax4(hf4 a, hf4 b) { return __builtin_elementwise_max(a, b); }
DEV void ce(hf4& a, hf4& b) { hf4 lo = hmin4(a, b); hf4 hi = hmax4(a, b); a = lo; b = hi; }
DEV hf2 pk2(float a, float b) { return __builtin_amdgcn_cvt_pkrtz(a, b); }
DEV hf4 cat(hf2 a, hf2 b) { return __builtin_shufflevector(a, b, 0, 1, 2, 3); }

DEV void sort3(hf4& a, hf4& b, hf4& c) { ce(a, b); ce(a, c); ce(b, c); }

// Batcher odd-even merges of small sorted sequences (verified exact in round 1).
DEV void merge21(hf4 a0, hf4 a1, hf4 b0, hf4 z[3]) {
    hf4 e0 = a0, e1 = b0; ce(e0, e1);
    z[0] = e0; z[1] = a1; z[2] = e1; ce(z[1], z[2]);
}
DEV void merge22(hf4 a0, hf4 a1, hf4 b0, hf4 b1, hf4 z[4]) {
    hf4 p0 = a0, p1 = b0; ce(p0, p1);
    hf4 q0 = a1, q1 = b1; ce(q0, q1);
    z[0] = p0; z[1] = q0; z[2] = p1; ce(z[1], z[2]); z[3] = q1;
}
DEV void merge31(hf4 a0, hf4 a1, hf4 a2, hf4 b0, hf4 z[4]) {
    hf4 e[3]; merge21(a0, a2, b0, e);
    z[0] = e[0]; z[1] = a1; z[2] = e[1]; ce(z[1], z[2]); z[3] = e[2];
}
DEV void merge32(hf4 a0, hf4 a1, hf4 a2, hf4 b0, hf4 b1, hf4 z[5]) {
    hf4 e[3]; merge21(a0, a2, b0, e);
    hf4 o0 = a1, o1 = b1; ce(o0, o1);
    z[0] = e[0];
    z[1] = o0; z[2] = e[1]; ce(z[1], z[2]);
    z[3] = o1; z[4] = e[2]; ce(z[3], z[4]);
}
DEV void merge33(const hf4 a[3], const hf4 b[3], hf4 z[6]) {
    hf4 e[4]; merge22(a[0], a[2], b[0], b[2], e);
    hf4 o0 = a[1], o1 = b[1]; ce(o0, o1);
    z[0] = e[0];
    z[1] = o0; z[2] = e[1]; ce(z[1], z[2]);
    z[3] = o1; z[4] = e[2]; ce(z[3], z[4]);
    z[5] = e[3];
}
DEV void merge63(const hf4 a[6], const hf4 b[3], hf4 z[9]) {
    hf4 e[5]; merge32(a[0], a[2], a[4], b[0], b[2], e);
    hf4 o[4]; merge31(a[1], a[3], a[5], b[1], o);
    z[0] = e[0];
    z[1] = o[0]; z[2] = e[1]; ce(z[1], z[2]);
    z[3] = o[1]; z[4] = e[2]; ce(z[3], z[4]);
    z[5] = o[2]; z[6] = e[3]; ce(z[5], z[6]);
    z[7] = o[3]; z[8] = e[4]; ce(z[7], z[8]);
}
DEV void merge44(const hf4 a[4], const hf4 b[4], hf4 z[8]) {
    hf4 e[4]; merge22(a[0], a[2], b[0], b[2], e);
    hf4 o[4]; merge22(a[1], a[3], b[1], b[3], o);
    z[0] = e[0];
    z[1] = o[0]; z[2] = e[1]; ce(z[1], z[2]);
    z[3] = o[1]; z[4] = e[2]; ce(z[3], z[4]);
    z[5] = o[2]; z[6] = e[3]; ce(z[5], z[6]);
    z[7] = o[3];
}
DEV void merge55(const hf4 a[5], const hf4 b[5], hf4 z[10]) {
    hf4 ae[3] = {a[0], a[2], a[4]}, be[3] = {b[0], b[2], b[4]};
    hf4 e[6]; merge33(ae, be, e);
    hf4 o[4]; merge22(a[1], a[3], b[1], b[3], o);
    z[0] = e[0];
    z[1] = o[0]; z[2] = e[1]; ce(z[1], z[2]);
    z[3] = o[1]; z[4] = e[2]; ce(z[3], z[4]);
    z[5] = o[2]; z[6] = e[3]; ce(z[5], z[6]);
    z[7] = o[3]; z[8] = e[4]; ce(z[7], z[8]);
    z[9] = e[5];
}
DEV void merge99(const hf4 a[9], const hf4 b[9], hf4 z[18]) {
    hf4 ae[5] = {a[0], a[2], a[4], a[6], a[8]};
    hf4 be[5] = {b[0], b[2], b[4], b[6], b[8]};
    hf4 e[10]; merge55(ae, be, e);
    hf4 ao[4] = {a[1], a[3], a[5], a[7]};
    hf4 bo[4] = {b[1], b[3], b[5], b[7]};
    hf4 o[8]; merge44(ao, bo, o);
    z[0] = e[0];
#pragma unroll
    for (int i = 0; i < 8; i++) {
        z[2 * i + 1] = o[i];
        z[2 * i + 2] = e[i + 1];
        ce(z[2 * i + 1], z[2 * i + 2]);
    }
    z[17] = e[9];
}

// rank-13-of-27 from merged-18 E and sorted-9 R:
//   med = min(E[13], min_i max(R[i], E[12-i]))   (verified exact in round 1)
DEV hf4 sel13(const hf4 E[18], const hf4 R[9]) {
    hf4 m = E[13];
#pragma unroll
    for (int i = 0; i < 9; i++) m = hmin4(m, hmax4(R[i], E[12 - i]));
    return m;
}

constexpr int Bb = 2, Dd = 160, Hh = 160, Ww = 160;
constexpr int HW = Hh * Ww;      // 25600
constexpr int CH = 8;            // z-planes per block pass
constexpr int NCH = Dd / CH;     // 20
constexpr int TX = 5, TY = 10;   // x tiles (32 cols), y tiles (16 rows)
constexpr int BROWS = 18;        // 16 + 2 y-halo
constexpr int BCOLS = 40;        // gcols x0t-4 .. x0t+35 (16B-aligned fills)
constexpr int PLANE = BROWS * BCOLS;  // 720 dwords = 180 float4
constexpr int NBUF = 6;               // LDS plane ring
constexpr int NBLK = Bb * NCH * TY * TX;  // 2000 blocks x 128 thr

typedef __attribute__((address_space(1))) const unsigned int gas_u32;
typedef __attribute__((address_space(3))) unsigned int las_u32;

__global__ __launch_bounds__(128, 2) void MedianPool3d_68994354642979_kernel(
    const float* __restrict__ in, float* __restrict__ out) {
    __shared__ float lds[NBUF * PLANE];  // 17280 B

    const int tid = threadIdx.x;
    int bid = blockIdx.x;
    const int tx = bid % TX; bid /= TX;
    const int ty = bid % TY; bid /= TY;
    const int chunk = bid % NCH;
    const int b = bid / NCH;

    const int lq = tid & 7;        // x-quad within tile
    const int ly = tid >> 3;       // y row within tile (0..15)
    const int y0 = ty * 16;
    const int x0t = tx * 32;
    const int z0 = chunk * CH;

    const float* base = in + (size_t)b * Dd * HW;
    float* ob = out + (size_t)b * Dd * HW;

    // Async fill of ring buffer (br % 6) with plane z0-1+br. Per-lane global
    // source (reflect/clamp applied); LDS dest = wave-uniform base + lane*16.
    auto fill = [&](int br) {
        int p = z0 - 1 + br;
        p = (p < 0) ? -p : (p > Dd - 1 ? 2 * Dd - 2 - p : p);  // z reflect
        const float* pp = base + (size_t)p * HW;
        float* buf = &lds[(br % NBUF) * PLANE];
#pragma unroll
        for (int k = 0; k < 2; k++) {
            int i = k * 128 + tid;           // float4 index in tile (0..179)
            if (i < PLANE / 4) {
                int r = i / 10, c4 = i % 10; // 18 rows x 10 float4
                int gy = y0 - 1 + r;
                gy = (gy < 0) ? 1 : (gy > Hh - 1 ? Hh - 2 : gy);   // y reflect
                int gx = x0t - 4 + 4 * c4;
                gx = (gx < 0) ? 0 : (gx > Ww - 4 ? Ww - 4 : gx);   // x clamp
                const float* src = pp + gy * Ww + gx;
                float* dst = buf + (size_t)(k * 128 + (tid & ~63)) * 4;
                __builtin_amdgcn_global_load_lds((gas_u32*)src, (las_u32*)dst,
                                                 16, 0, 0);
            }
        }
    };

    // Per-thread tap columns in the LDS tile (col c <-> gcol x0t-4+c).
    // x-reflect folds into the column choice at global edges.
    const int lcol = (tx == 0 && lq == 0) ? 1 : 3 + 4 * lq;        // left tap
    const int rcol = (tx == TX - 1 && lq == 7) ? 34 : 8 + 4 * lq;  // right tap
    const int mco = 4 + 4 * lq;                                    // center 4

    auto sortp = [&](int br, hf4(&M)[9]) {
        const float* buf = &lds[(br % NBUF) * PLANE];
        hf4 r[3][3];
#pragma unroll
        for (int i = 0; i < 3; i++) {
            const float* rp = buf + (ly + i) * BCOLS;
            float4 v = *reinterpret_cast<const float4*>(rp + mco);  // ds_read_b128
            float a = rp[lcol], d = rp[rcol];
            hf2 pAL = pk2(a, v.x);
            hf2 pAC = pk2(v.x, v.y);
            hf2 pSH = pk2(v.y, v.z);
            hf2 pBC = pk2(v.z, v.w);
            hf2 pBR = pk2(v.w, d);
            r[i][0] = cat(pAL, pSH);
            r[i][1] = cat(pAC, pBC);
            r[i][2] = cat(pSH, pBR);
            sort3(r[i][0], r[i][1], r[i][2]);
        }
        hf4 s6[6]; merge33(r[0], r[1], s6);
        merge63(s6, r[2], M);
    };

    // ---- prologue: stage planes rel 0..4 (z0-1 .. z0+3), sort first three
    fill(0); fill(1); fill(2); fill(3); fill(4);
    __syncthreads();                       // fills 0..4 landed
    hf4 SS[4][9];
    sortp(0, SS[0]);  // S[z0-1]
    sortp(1, SS[1]);  // S[z0]
    sortp(2, SS[2]);  // S[z0+1]
    __syncthreads();                       // bufs 0..2 reads done -> refillable

#pragma unroll
    for (int j = 0; j < CH / 2; j++) {
        const int z = z0 + 2 * j;
        const int sA = (2 * j) & 3;      // S[z-1]
        const int sB = (2 * j + 1) & 3;  // S[z]
        const int sC = (2 * j + 2) & 3;  // S[z+1]
        const int sD = (2 * j + 3) & 3;  // S[z+2]

        // prefetch fills for planes consumed NEXT iteration (rel 2j+5, 2j+6);
        // their latency hides under this iteration's sorts+merges.
        if (2 * j + 5 <= CH + 1) fill(2 * j + 5);
        if (2 * j + 6 <= CH + 1) fill(2 * j + 6);

        sortp(2 * j + 3, SS[sD]);        // S[z+2] from LDS (filled last iter)

        hf4 E[18];
        merge99(SS[sB], SS[sC], E);      // shared pair (z, z+1) -> used twice
        hf4 m0 = sel13(E, SS[sA]);       // output z   : third plane z-1
        hf4 m1 = sel13(E, SS[sD]);       // output z+1 : third plane z+2

        float* o0 = ob + (size_t)z * HW + (y0 + ly) * Ww + x0t + 4 * lq;
        float* o1 = o0 + HW;
        *reinterpret_cast<float4*>(o0) =
            make_float4((float)m0.x, (float)m0.y, (float)m0.z, (float)m0.w);
        *reinterpret_cast<float4*>(o1) =
            make_float4((float)m1.x, (float)m1.y, (float)m1.z, (float)m1.w);

        if (j < CH / 2 - 1) sortp(2 * j + 4, SS[sA]);  // S[z+3] into retired slot

        __syncthreads();  // drain this iter's fills; fence buf reuse
    }
}

extern "C" void kernel_launch(void* const* d_in, const int* in_sizes, int n_in,
                              void* d_out, int out_size, void* d_ws, size_t ws_size,
                              hipStream_t stream) {
    const float* x = (const float*)d_in[0];
    float* out = (float*)d_out;
    MedianPool3d_68994354642979_kernel<<<NBLK, 128, 0, stream>>>(x, out);
}

// Round 8
// 27.467 us; speedup vs baseline: 1.1916x; 1.1916x over previous
//
#include <hip/hip_runtime.h>

// 3D median filter 3x3x3, stride 1, reflect padding.
// x: (2, 1, 160, 160, 160) fp32 -> same shape. Median = rank 13 (0-based) of 27.
// Round 7: R5 compute (hf4 packed-f16, 4 x-outputs/thread, merge99 shared by
// 2 z-outputs) + ENFORCED software pipeline: raw plane loads into RT0/RT1
// one iteration ahead, pinned with sched_barrier(0) so the register-pressure
// scheduler cannot sink them into their consumers (R3/R5 failure mode).

typedef __fp16 hf2 __attribute__((ext_vector_type(2)));
typedef __fp16 hf4 __attribute__((ext_vector_type(4)));

#define DEV __device__ __forceinline__
#define SCHED_FENCE() __builtin_amdgcn_sched_barrier(0)

DEV hf4 hmin4(hf4 a, hf4 b) { return __builtin_elementwise_min(a, b); }
DEV hf4 hmax4(hf4 a, hf4 b) { return __builtin_elementwise_max(a, b); }
DEV void ce(hf4& a, hf4& b) { hf4 lo = hmin4(a, b); hf4 hi = hmax4(a, b); a = lo; b = hi; }
DEV hf2 pk2(float a, float b) { return __builtin_amdgcn_cvt_pkrtz(a, b); }
DEV hf4 cat(hf2 a, hf2 b) { return __builtin_shufflevector(a, b, 0, 1, 2, 3); }

DEV void sort3(hf4& a, hf4& b, hf4& c) { ce(a, b); ce(a, c); ce(b, c); }

// Batcher odd-even merges of small sorted sequences (verified exact, rounds 1-6).
DEV void merge21(hf4 a0, hf4 a1, hf4 b0, hf4 z[3]) {
    hf4 e0 = a0, e1 = b0; ce(e0, e1);
    z[0] = e0; z[1] = a1; z[2] = e1; ce(z[1], z[2]);
}
DEV void merge22(hf4 a0, hf4 a1, hf4 b0, hf4 b1, hf4 z[4]) {
    hf4 p0 = a0, p1 = b0; ce(p0, p1);
    hf4 q0 = a1, q1 = b1; ce(q0, q1);
    z[0] = p0; z[1] = q0; z[2] = p1; ce(z[1], z[2]); z[3] = q1;
}
DEV void merge31(hf4 a0, hf4 a1, hf4 a2, hf4 b0, hf4 z[4]) {
    hf4 e[3]; merge21(a0, a2, b0, e);
    z[0] = e[0]; z[1] = a1; z[2] = e[1]; ce(z[1], z[2]); z[3] = e[2];
}
DEV void merge32(hf4 a0, hf4 a1, hf4 a2, hf4 b0, hf4 b1, hf4 z[5]) {
    hf4 e[3]; merge21(a0, a2, b0, e);
    hf4 o0 = a1, o1 = b1; ce(o0, o1);
    z[0] = e[0];
    z[1] = o0; z[2] = e[1]; ce(z[1], z[2]);
    z[3] = o1; z[4] = e[2]; ce(z[3], z[4]);
}
DEV void merge33(const hf4 a[3], const hf4 b[3], hf4 z[6]) {
    hf4 e[4]; merge22(a[0], a[2], b[0], b[2], e);
    hf4 o0 = a[1], o1 = b[1]; ce(o0, o1);
    z[0] = e[0];
    z[1] = o0; z[2] = e[1]; ce(z[1], z[2]);
    z[3] = o1; z[4] = e[2]; ce(z[3], z[4]);
    z[5] = e[3];
}
DEV void merge63(const hf4 a[6], const hf4 b[3], hf4 z[9]) {
    hf4 e[5]; merge32(a[0], a[2], a[4], b[0], b[2], e);
    hf4 o[4]; merge31(a[1], a[3], a[5], b[1], o);
    z[0] = e[0];
    z[1] = o[0]; z[2] = e[1]; ce(z[1], z[2]);
    z[3] = o[1]; z[4] = e[2]; ce(z[3], z[4]);
    z[5] = o[2]; z[6] = e[3]; ce(z[5], z[6]);
    z[7] = o[3]; z[8] = e[4]; ce(z[7], z[8]);
}
DEV void merge44(const hf4 a[4], const hf4 b[4], hf4 z[8]) {
    hf4 e[4]; merge22(a[0], a[2], b[0], b[2], e);
    hf4 o[4]; merge22(a[1], a[3], b[1], b[3], o);
    z[0] = e[0];
    z[1] = o[0]; z[2] = e[1]; ce(z[1], z[2]);
    z[3] = o[1]; z[4] = e[2]; ce(z[3], z[4]);
    z[5] = o[2]; z[6] = e[3]; ce(z[5], z[6]);
    z[7] = o[3];
}
DEV void merge55(const hf4 a[5], const hf4 b[5], hf4 z[10]) {
    hf4 ae[3] = {a[0], a[2], a[4]}, be[3] = {b[0], b[2], b[4]};
    hf4 e[6]; merge33(ae, be, e);
    hf4 o[4]; merge22(a[1], a[3], b[1], b[3], o);
    z[0] = e[0];
    z[1] = o[0]; z[2] = e[1]; ce(z[1], z[2]);
    z[3] = o[1]; z[4] = e[2]; ce(z[3], z[4]);
    z[5] = o[2]; z[6] = e[3]; ce(z[5], z[6]);
    z[7] = o[3]; z[8] = e[4]; ce(z[7], z[8]);
    z[9] = e[5];
}
DEV void merge99(const hf4 a[9], const hf4 b[9], hf4 z[18]) {
    hf4 ae[5] = {a[0], a[2], a[4], a[6], a[8]};
    hf4 be[5] = {b[0], b[2], b[4], b[6], b[8]};
    hf4 e[10]; merge55(ae, be, e);
    hf4 ao[4] = {a[1], a[3], a[5], a[7]};
    hf4 bo[4] = {b[1], b[3], b[5], b[7]};
    hf4 o[8]; merge44(ao, bo, o);
    z[0] = e[0];
#pragma unroll
    for (int i = 0; i < 8; i++) {
        z[2 * i + 1] = o[i];
        z[2 * i + 2] = e[i + 1];
        ce(z[2 * i + 1], z[2 * i + 2]);
    }
    z[17] = e[9];
}

// Raw taps (6 per row: L, c0..c3, R) of the 3x3x(4-wide) window -> 18 floats.
DEV void load18(const float* __restrict__ pb, const int ro[3], int cL, int x0, int cR,
                float R[18]) {
#pragma unroll
    for (int i = 0; i < 3; i++) {
        const float* p = pb + ro[i];
        R[i * 6 + 0] = p[cL];
        float4 v = *reinterpret_cast<const float4*>(p + x0);  // 16B-aligned
        R[i * 6 + 1] = v.x; R[i * 6 + 2] = v.y;
        R[i * 6 + 3] = v.z; R[i * 6 + 4] = v.w;
        R[i * 6 + 5] = p[cR];
    }
}

// 18 raw floats -> packed rows -> sorted-9 (4-wide packed).
DEV void sortp(const float R[18], hf4 M[9]) {
    hf4 r[3][3];
#pragma unroll
    for (int i = 0; i < 3; i++) {
        const float* q = R + i * 6;
        hf2 pAL = pk2(q[0], q[1]);
        hf2 pAC = pk2(q[1], q[2]);
        hf2 pSH = pk2(q[2], q[3]);   // right-taps of pair A == left-taps of pair B
        hf2 pBC = pk2(q[3], q[4]);
        hf2 pBR = pk2(q[4], q[5]);
        r[i][0] = cat(pAL, pSH);
        r[i][1] = cat(pAC, pBC);
        r[i][2] = cat(pSH, pBR);
        sort3(r[i][0], r[i][1], r[i][2]);
    }
    hf4 s6[6]; merge33(r[0], r[1], s6);
    merge63(s6, r[2], M);
}

// rank-13-of-27 from merged-18 E and sorted-9 R:
//   med = min(E[13], min_i max(R[i], E[12-i]))   (verified exact in round 1)
DEV hf4 sel13(const hf4 E[18], const hf4 R[9]) {
    hf4 m = E[13];
#pragma unroll
    for (int i = 0; i < 9; i++) m = hmin4(m, hmax4(R[i], E[12 - i]));
    return m;
}

constexpr int Bb = 2, Dd = 160, Hh = 160, Ww = 160;
constexpr int HW = Hh * Ww;            // 25600
constexpr int WQ = Ww / 4;             // 40 x-quads per row
constexpr int CH = 8;                  // z-chunk per thread (even)
constexpr int NCH = Dd / CH;           // 20
constexpr int TOTAL = Bb * NCH * Hh * WQ;  // 256,000 threads = 4000 waves

__global__ __launch_bounds__(256, 2) void MedianPool3d_68994354642979_kernel(
    const float* __restrict__ in, float* __restrict__ out) {
    int tid = blockIdx.x * 256 + threadIdx.x;
    int q = tid % WQ;
    int rest = tid / WQ;
    int y = rest % Hh;
    rest /= Hh;
    int chunk = rest % NCH;
    int b = rest / NCH;
    int x0 = q * 4;

    // reflect padding (jnp.pad mode="reflect", pad=1)
    int ym = (y == 0) ? 1 : y - 1;
    int yp = (y == Hh - 1) ? Hh - 2 : y + 1;
    int ro[3] = {ym * Ww, y * Ww, yp * Ww};
    int cL = (x0 == 0) ? 1 : x0 - 1;                 // left tap of col x0
    int cR = (x0 + 4 == Ww) ? (Ww - 2) : x0 + 4;     // right tap of col x0+3

    const float* base = in + (size_t)b * Dd * HW;
    float* ob = out + (size_t)b * Dd * HW;
    int z0 = chunk * CH;

    auto planeptr = [&](int p) {
        if (p < 0) p = -p;                 // reflect(-1) = 1
        if (p >= Dd) p = 2 * Dd - 2 - p;   // reflect(160) = 158
        return base + (size_t)p * HW;
    };

    // 4-slot ring of sorted planes: plane rel r (r in [-1, CH]) -> slot (r+1)&3.
    hf4 SS[4][9];
    // Raw prefetch buffers: RT0 holds even-rel planes (2,4,6,8), RT1 odd (3,5,7).
    float RT0[18], RT1[18];

    {   // prologue: issue rel -1, 0, 1, 2 together; sort -1,0,1; issue rel 3.
        float P0[18], P1[18];
        load18(planeptr(z0 - 1), ro, cL, x0, cR, P0);
        load18(planeptr(z0),     ro, cL, x0, cR, P1);
        load18(planeptr(z0 + 1), ro, cL, x0, cR, RT1);
        load18(planeptr(z0 + 2), ro, cL, x0, cR, RT0);
        SCHED_FENCE();
        sortp(P0, SS[0]);   // S[z0-1]
        sortp(P1, SS[1]);   // S[z0]
        sortp(RT1, SS[2]);  // S[z0+1]
        load18(planeptr(z0 + 3), ro, cL, x0, cR, RT1);
        SCHED_FENCE();
    }

#pragma unroll
    for (int j = 0; j < CH / 2; j++) {
        const int z = z0 + 2 * j;
        const int sA = (2 * j) & 3;      // S[z-1]
        const int sB = (2 * j + 1) & 3;  // S[z]
        const int sC = (2 * j + 2) & 3;  // S[z+1]
        const int sD = (2 * j + 3) & 3;  // S[z+2]

        // consume RT0 (plane rel 2j+2, loaded a full iteration ago)
        sortp(RT0, SS[sD]);
        if (j <= 2)  // prefetch plane rel 2j+4 into RT0; pinned by the fence
            load18(planeptr(z + 4), ro, cL, x0, cR, RT0);
        SCHED_FENCE();

        hf4 E[18];
        merge99(SS[sB], SS[sC], E);      // shared pair (z, z+1) -> used twice
        hf4 m0 = sel13(E, SS[sA]);       // output z   : third plane z-1
        hf4 m1 = sel13(E, SS[sD]);       // output z+1 : third plane z+2

        float* o0 = ob + (size_t)z * HW + ro[1] + x0;   // 16B-aligned
        float* o1 = o0 + HW;
        *reinterpret_cast<float4*>(o0) =
            make_float4((float)m0.x, (float)m0.y, (float)m0.z, (float)m0.w);
        *reinterpret_cast<float4*>(o1) =
            make_float4((float)m1.x, (float)m1.y, (float)m1.z, (float)m1.w);

        if (j <= 2)  // consume RT1 (plane rel 2j+3) into the retired slot
            sortp(RT1, SS[sA]);
        if (j <= 1)  // prefetch plane rel 2j+5 into RT1
            load18(planeptr(z + 5), ro, cL, x0, cR, RT1);
        SCHED_FENCE();
    }
}

extern "C" void kernel_launch(void* const* d_in, const int* in_sizes, int n_in,
                              void* d_out, int out_size, void* d_ws, size_t ws_size,
                              hipStream_t stream) {
    const float* x = (const float*)d_in[0];
    float* out = (float*)d_out;
    constexpr int threads = 256;
    constexpr int blocks = TOTAL / threads;  // 1000 exactly
    MedianPool3d_68994354642979_kernel<<<blocks, threads, 0, stream>>>(x, out);
}